// Round 1
// baseline (126.012 us; speedup 1.0000x reference)
//
#include <hip/hip_runtime.h>
#include <hip/hip_cooperative_groups.h>
#include <math.h>

namespace cg = cooperative_groups;

#define NN 384
#define NT 24              // NN/16 tiles per dim
#define NTILES (NT * NT)   // 576
#define NBLK 144           // cooperative grid: 144 blocks x 256 thr = 576 waves = 1 wave/tile
#define TPB 256

typedef __attribute__((ext_vector_type(8))) short short8;   // 8 bf16 (4 VGPRs)
typedef __attribute__((ext_vector_type(4))) float v4f;      // 4 fp32 acc
typedef __attribute__((ext_vector_type(4))) int int4v;
typedef __attribute__((ext_vector_type(4))) float float4v;
typedef __attribute__((ext_vector_type(4))) short short4v;

__device__ __forceinline__ unsigned short f2bf(float f) {
    union { float f; unsigned u; } v; v.f = f;
    return (unsigned short)((v.u + 0x7FFFu + ((v.u >> 16) & 1u)) >> 16);
}

// Single fused cooperative kernel, 3 phases separated by grid.sync():
//   A: P = gate(adj, i!=j) * exp(-lam*dist)           -> P32, P16, PT16
//   B: S = P*P (MFMA); V = od/(P+S) gated             -> V16, VT16 (+V,P in regs)
//   C: W = V*P^T, U = P^T*V; out = P .* (V + W + U)
// Phase-C wave covers the SAME output tile as its phase-B tile, so P32/V values
// for the epilogue stay in registers across the sync (no V32 round-trip).
__global__ __launch_bounds__(TPB) void fused(
    const float* __restrict__ od, const int* __restrict__ adj,
    const float* __restrict__ dist, const int* __restrict__ lam_ptr,
    float* __restrict__ out,
    unsigned short* __restrict__ P16, unsigned short* __restrict__ PT16,
    unsigned short* __restrict__ V16, unsigned short* __restrict__ VT16,
    float* __restrict__ P32)
{
    cg::grid_group grid = cg::this_grid();
    const float lam = (float)(*lam_ptr);

    // ---- Phase A: build P (coalesced 16B loads, 4 consecutive elems/thread) ----
    {
        int tid = blockIdx.x * TPB + threadIdx.x;   // 36864 threads
        int idx0 = tid * 4;                          // NN*NN = 147456 = 36864*4
        int i = idx0 / NN;
        int jb = idx0 - i * NN;                      // multiple of 4, no row crossing
        int4v   a4 = *(const int4v*)(adj + idx0);
        float4v d4 = *(const float4v*)(dist + idx0);
        float4v p4;
        short4v h4;
#pragma unroll
        for (int u = 0; u < 4; ++u) {
            int j = jb + u;
            float p = (a4[u] > 0 && i != j) ? __expf(-lam * d4[u]) : 0.0f;
            p4[u] = p;
            unsigned short h = f2bf(p);
            h4[u] = (short)h;
            PT16[j * NN + i] = h;                    // transposed scatter (L2-backed)
        }
        *(float4v*)(P32 + idx0) = p4;
        *(short4v*)((short*)P16 + idx0) = h4;
    }

    grid.sync();

    // tile/lane geometry shared by phases B and C
    const int t = blockIdx.x * 4 + (threadIdx.x >> 6);   // wave -> 16x16 tile
    const int lane = threadIdx.x & 63;
    const int i0 = (t / NT) * 16, j0 = (t % NT) * 16;
    const int col = lane & 15, quad = lane >> 4;

    float pv[4], vv[4];                                  // carried into phase C

    // ---- Phase B: S = P*P ; V = od/(P+S) gated ----
    {
        v4f acc0 = {0.f, 0.f, 0.f, 0.f};
        v4f acc1 = {0.f, 0.f, 0.f, 0.f};
        const short8* arow = (const short8*)(P16 + (i0 + col) * NN + quad * 8);
        const short8* brow = (const short8*)(PT16 + (j0 + col) * NN + quad * 8);
#pragma unroll
        for (int k0 = 0; k0 < NN / 64; ++k0) {           // 6 double-steps, 2 indep chains
            acc0 = __builtin_amdgcn_mfma_f32_16x16x32_bf16(arow[k0 * 8],     brow[k0 * 8],     acc0, 0, 0, 0);
            acc1 = __builtin_amdgcn_mfma_f32_16x16x32_bf16(arow[k0 * 8 + 4], brow[k0 * 8 + 4], acc1, 0, 0, 0);
        }
#pragma unroll
        for (int r = 0; r < 4; ++r) {
            int i = i0 + quad * 4 + r, j = j0 + col;
            int idx = i * NN + j;
            float p = P32[idx];
            float denom = p + acc0[r] + acc1[r];
            float o = od[idx];
            float v = (i != j && o > 0.0f && denom > 0.0f) ? o / denom : 0.0f;
            pv[r] = p;
            vv[r] = v;
            unsigned short h = f2bf(v);
            V16[idx] = h;
            VT16[j * NN + i] = h;
        }
    }

    grid.sync();

    // ---- Phase C: W = V*P^T, U = P^T*V ; out = P .* (V + W + U) ----
    {
        v4f accW = {0.f, 0.f, 0.f, 0.f};
        v4f accU = {0.f, 0.f, 0.f, 0.f};
        const short8* aW = (const short8*)(V16  + (i0 + col) * NN + quad * 8);
        const short8* bW = (const short8*)(P16  + (j0 + col) * NN + quad * 8);
        const short8* aU = (const short8*)(PT16 + (i0 + col) * NN + quad * 8);
        const short8* bU = (const short8*)(VT16 + (j0 + col) * NN + quad * 8);
#pragma unroll
        for (int k0 = 0; k0 < NN / 32; ++k0) {           // 12 steps, 2 indep chains
            accW = __builtin_amdgcn_mfma_f32_16x16x32_bf16(aW[k0 * 4], bW[k0 * 4], accW, 0, 0, 0);
            accU = __builtin_amdgcn_mfma_f32_16x16x32_bf16(aU[k0 * 4], bU[k0 * 4], accU, 0, 0, 0);
        }
#pragma unroll
        for (int r = 0; r < 4; ++r) {
            int i = i0 + quad * 4 + r, j = j0 + col;
            out[i * NN + j] = pv[r] * (vv[r] + accW[r] + accU[r]);
        }
    }
}

extern "C" void kernel_launch(void* const* d_in, const int* in_sizes, int n_in,
                              void* d_out, int out_size, void* d_ws, size_t ws_size,
                              hipStream_t stream) {
    const float* od   = (const float*)d_in[0];
    const int*   adj  = (const int*)d_in[1];
    const float* dist = (const float*)d_in[2];
    const int*   lam  = (const int*)d_in[3];
    // d_in[4] = capacity (unused: max_iter=1, BPR update happens after output)
    float* out = (float*)d_out;

    // workspace layout (16B-aligned; bf16 arrays are NN*NN*2 = 294912 B each)
    unsigned short* P16  = (unsigned short*)d_ws;
    unsigned short* PT16 = P16 + NN * NN;
    unsigned short* V16  = PT16 + NN * NN;
    unsigned short* VT16 = V16 + NN * NN;
    float*          P32  = (float*)(VT16 + NN * NN);

    void* args[] = {(void*)&od, (void*)&adj, (void*)&dist, (void*)&lam, (void*)&out,
                    (void*)&P16, (void*)&PT16, (void*)&V16, (void*)&VT16, (void*)&P32};
    hipLaunchCooperativeKernel((void*)fused, dim3(NBLK), dim3(TPB), args, 0, stream);
}

// Round 3
// 81.317 us; speedup vs baseline: 1.5496x; 1.5496x over previous
//
#include <hip/hip_runtime.h>
#include <math.h>

#define NN 384
#define NT 24              // NN/16 tiles per dim
#define NTILES (NT * NT)   // 576
#define PAD 392            // LDS row stride (bf16 elems): 784 B -> 16B-aligned rows for ds_read_b128,
                           // 196 dwords -> consecutive rows start 4 banks apart

typedef __attribute__((ext_vector_type(8))) short short8;   // 8 bf16 (4 VGPRs)
typedef __attribute__((ext_vector_type(4))) float v4f;      // 4 fp32 acc
typedef __attribute__((ext_vector_type(4))) int int4v;
typedef __attribute__((ext_vector_type(4))) float float4v;
typedef __attribute__((ext_vector_type(4))) short short4v;

__device__ __forceinline__ unsigned short f2bf(float f) {
    union { float f; unsigned u; } v; v.f = f;
    return (unsigned short)((v.u + 0x7FFFu + ((v.u >> 16) & 1u)) >> 16);
}

// K1': fused {build P} + {S = P*P, V = od/(P+S)}.
// No grid barrier needed: each block REBUILDS the P row-band (As) and P col-band
// (Bs, transposed) it needs straight from adj/dist into LDS (P is a cheap
// closed-form elementwise function). Block = 256 thr = 4 waves = 2x2 tiles of 16x16.
// Edge blocks (SJ==0 / SI==0) publish P16 / PT16 globally for the flows kernel.
__global__ __launch_bounds__(256) void pv_kernel(
    const float* __restrict__ od, const int* __restrict__ adj,
    const float* __restrict__ dist, const int* __restrict__ lam_ptr,
    unsigned short* __restrict__ P16, unsigned short* __restrict__ PT16,
    unsigned short* __restrict__ V16, unsigned short* __restrict__ VT16,
    float* __restrict__ V32)
{
    __shared__ __align__(16) unsigned short As[32][PAD];  // As[m][k]  = P[i0+m][k]
    __shared__ __align__(16) unsigned short Bs[32][PAD];  // Bs[n][k]  = P[k][j0+n]

    const int SI = blockIdx.x / 12, SJ = blockIdx.x % 12;  // 12x12 super-tiles of 32x32
    const int i0 = SI * 32, j0 = SJ * 32;
    const float lam = (float)(*lam_ptr);
    const int t = threadIdx.x;

    // ---- stage A band: P rows [i0, i0+32), coalesced row reads ----
    {
        const int m = t >> 3, ko = (t & 7) * 48;           // 8 threads per row, 48 elems each
        const int gi = i0 + m;
        const float4v* dp = (const float4v*)(dist + gi * NN + ko);
        const int4v*   ap = (const int4v*)(adj + gi * NN + ko);
#pragma unroll
        for (int u = 0; u < 12; ++u) {
            float4v d4 = dp[u];
            int4v   a4 = ap[u];
            short4v h4;
#pragma unroll
            for (int v = 0; v < 4; ++v) {
                int j = ko + u * 4 + v;
                float p = (a4[v] > 0 && gi != j) ? __expf(-lam * d4[v]) : 0.0f;
                h4[v] = (short)f2bf(p);
            }
            *(short4v*)&As[m][ko + u * 4] = h4;
        }
    }

    // ---- stage B band transposed: Bs[n][k] = P[k][j0+n], coalesced row-chunk reads ----
    {
        const int half = t & 1;                             // which 16-col half
        const int kb = t >> 1;                              // 0..127
#pragma unroll
        for (int pp = 0; pp < 3; ++pp) {
            int k = pp * 128 + kb;
            const float4v* dp = (const float4v*)(dist + k * NN + j0 + half * 16);
            const int4v*   ap = (const int4v*)(adj + k * NN + j0 + half * 16);
#pragma unroll
            for (int q = 0; q < 4; ++q) {
                float4v d4 = dp[q];
                int4v   a4 = ap[q];
#pragma unroll
                for (int v = 0; v < 4; ++v) {
                    int n = half * 16 + q * 4 + v;
                    int j = j0 + n;
                    float p = (a4[v] > 0 && k != j) ? __expf(-lam * d4[v]) : 0.0f;
                    Bs[n][k] = f2bf(p);                     // byte-granular LDS write, no RMW race
                }
            }
        }
    }

    __syncthreads();

    // ---- publish P16 / PT16 (each row written by exactly one block) ----
    if (SJ == 0) {
        const int m = t >> 3, ko = (t & 7) * 48;
#pragma unroll
        for (int u = 0; u < 12; ++u)
            *(short4v*)(P16 + (i0 + m) * NN + ko + u * 4) = *(short4v*)&As[m][ko + u * 4];
    }
    if (SI == 0) {
        const int n = t >> 3, ko = (t & 7) * 48;
#pragma unroll
        for (int u = 0; u < 12; ++u)
            *(short4v*)(PT16 + (j0 + n) * NN + ko + u * 4) = *(short4v*)&Bs[n][ko + u * 4];
    }

    // ---- per-wave MFMA: S tile, then V epilogue ----
    const int w = t >> 6, lane = t & 63;
    const int wi = w >> 1, wj = w & 1;                      // 2x2 tile arrangement
    const int col = lane & 15, quad = lane >> 4;
    const unsigned short* arow = &As[wi * 16 + col][0];
    const unsigned short* brow = &Bs[wj * 16 + col][0];
    v4f acc0 = {0.f, 0.f, 0.f, 0.f};
    v4f acc1 = {0.f, 0.f, 0.f, 0.f};
#pragma unroll
    for (int k0 = 0; k0 < NN / 64; ++k0) {                  // 6 double-steps, 2 indep chains
        short8 a0 = *(const short8*)(arow + k0 * 64 + quad * 8);
        short8 b0 = *(const short8*)(brow + k0 * 64 + quad * 8);
        short8 a1 = *(const short8*)(arow + k0 * 64 + 32 + quad * 8);
        short8 b1 = *(const short8*)(brow + k0 * 64 + 32 + quad * 8);
        acc0 = __builtin_amdgcn_mfma_f32_16x16x32_bf16(a0, b0, acc0, 0, 0, 0);
        acc1 = __builtin_amdgcn_mfma_f32_16x16x32_bf16(a1, b1, acc1, 0, 0, 0);
    }
#pragma unroll
    for (int r = 0; r < 4; ++r) {
        int i = i0 + wi * 16 + quad * 4 + r, j = j0 + wj * 16 + col;
        int idx = i * NN + j;
        float p = (adj[idx] > 0 && i != j) ? __expf(-lam * dist[idx]) : 0.0f;  // exact fp32 P
        float denom = p + acc0[r] + acc1[r];
        float o = od[idx];
        float v = (i != j && o > 0.0f && denom > 0.0f) ? o / denom : 0.0f;
        V32[idx] = v;
        unsigned short h = f2bf(v);
        V16[idx] = h;
        VT16[j * NN + i] = h;
    }
}

// K2: one wave per 16x16 tile: W = V*P^T (A=V16 rows, Bt=P16 rows),
// U = P^T*V (A=PT16 rows, Bt=VT16 rows); out = p_exact*(V32 + W + U).
// (Round-0 proven kernel, unchanged.)
__global__ __launch_bounds__(64) void flows_kernel(const unsigned short* __restrict__ P16,
                                                   const unsigned short* __restrict__ PT16,
                                                   const unsigned short* __restrict__ V16,
                                                   const unsigned short* __restrict__ VT16,
                                                   const float* __restrict__ V32,
                                                   const int* __restrict__ adj,
                                                   const float* __restrict__ dist,
                                                   const int* __restrict__ lam_ptr,
                                                   float* __restrict__ out) {
    int t = blockIdx.x;
    int i0 = (t / NT) * 16, j0 = (t % NT) * 16;
    int lane = threadIdx.x;
    int col = lane & 15, quad = lane >> 4;
    v4f accW = {0.f, 0.f, 0.f, 0.f};
    v4f accU = {0.f, 0.f, 0.f, 0.f};
    const short8* aW = (const short8*)(V16 + (i0 + col) * NN + quad * 8);
    const short8* bW = (const short8*)(P16 + (j0 + col) * NN + quad * 8);
    const short8* aU = (const short8*)(PT16 + (i0 + col) * NN + quad * 8);
    const short8* bU = (const short8*)(VT16 + (j0 + col) * NN + quad * 8);
#pragma unroll
    for (int k0 = 0; k0 < NN / 32; ++k0) {
        short8 a0 = aW[k0 * 4];
        short8 b0 = bW[k0 * 4];
        short8 a1 = aU[k0 * 4];
        short8 b1 = bU[k0 * 4];
        accW = __builtin_amdgcn_mfma_f32_16x16x32_bf16(a0, b0, accW, 0, 0, 0);
        accU = __builtin_amdgcn_mfma_f32_16x16x32_bf16(a1, b1, accU, 0, 0, 0);
    }
    float lam = (float)(*lam_ptr);
#pragma unroll
    for (int r = 0; r < 4; ++r) {
        int i = i0 + quad * 4 + r, j = j0 + col;
        int idx = i * NN + j;
        float p = (adj[idx] > 0 && i != j) ? __expf(-lam * dist[idx]) : 0.0f;
        out[idx] = p * (V32[idx] + accW[r] + accU[r]);
    }
}

extern "C" void kernel_launch(void* const* d_in, const int* in_sizes, int n_in,
                              void* d_out, int out_size, void* d_ws, size_t ws_size,
                              hipStream_t stream) {
    const float* od   = (const float*)d_in[0];
    const int*   adj  = (const int*)d_in[1];
    const float* dist = (const float*)d_in[2];
    const int*   lam  = (const int*)d_in[3];
    // d_in[4] = capacity (unused: max_iter=1, BPR update happens after output)
    float* out = (float*)d_out;

    // workspace layout (16B-aligned; bf16 arrays are NN*NN*2 = 294912 B each)
    unsigned short* P16  = (unsigned short*)d_ws;
    unsigned short* PT16 = P16 + NN * NN;
    unsigned short* V16  = PT16 + NN * NN;
    unsigned short* VT16 = V16 + NN * NN;
    float*          V32  = (float*)(VT16 + NN * NN);

    pv_kernel<<<144, 256, 0, stream>>>(od, adj, dist, lam, P16, PT16, V16, VT16, V32);
    flows_kernel<<<NTILES, 64, 0, stream>>>(P16, PT16, V16, VT16, V32, adj, dist, lam, out);
}

// Round 4
// 76.354 us; speedup vs baseline: 1.6504x; 1.0650x over previous
//
#include <hip/hip_runtime.h>
#include <math.h>

#define NN 384
#define NT 24              // NN/16 tiles per dim
#define NTILES (NT * NT)   // 576
#define NBLK 144           // 4 waves/block -> 144 blocks cover 576 tiles

typedef __attribute__((ext_vector_type(8))) short short8;   // 8 bf16 (4 VGPRs)
typedef __attribute__((ext_vector_type(4))) float v4f;      // 4 fp32 acc
typedef __attribute__((ext_vector_type(4))) int int4v;
typedef __attribute__((ext_vector_type(4))) float float4v;
typedef __attribute__((ext_vector_type(4))) short short4v;

__device__ __forceinline__ unsigned short f2bf(float f) {
    union { float f; unsigned u; } v; v.f = f;
    return (unsigned short)((v.u + 0x7FFFu + ((v.u >> 16) & 1u)) >> 16);
}
__device__ __forceinline__ float bf2f(unsigned short h) {
    union { unsigned u; float f; } v; v.u = ((unsigned)h) << 16;
    return v.f;
}

// K1: P16[i][j] = bf16(exp(-lam*dist) gated), PT16 = transpose.
// Vectorized x4: 144 blocks x 256 thr, 16B coalesced loads + 8B P16 stores.
// PT16 is a 2B transposed scatter (unavoidable; L2-backed).
__global__ __launch_bounds__(256) void build_p_kernel(const int* __restrict__ adj,
                                                      const float* __restrict__ dist,
                                                      const int* __restrict__ lam_ptr,
                                                      unsigned short* __restrict__ P16,
                                                      unsigned short* __restrict__ PT16) {
    const float lam = (float)(*lam_ptr);
    int tid = blockIdx.x * 256 + threadIdx.x;   // 36864 threads
    int idx0 = tid * 4;                          // NN*NN = 147456 = 36864*4
    int i = idx0 / NN;
    int jb = idx0 - i * NN;                      // multiple of 4 -> no row crossing
    int4v   a4 = *(const int4v*)(adj + idx0);
    float4v d4 = *(const float4v*)(dist + idx0);
    short4v h4;
#pragma unroll
    for (int u = 0; u < 4; ++u) {
        int j = jb + u;
        float p = (a4[u] > 0 && i != j) ? __expf(-lam * d4[u]) : 0.0f;
        unsigned short h = f2bf(p);
        h4[u] = (short)h;
        PT16[j * NN + i] = h;
    }
    *(short4v*)(P16 + idx0) = h4;
}

// K2: one wave per 16x16 tile of S = P*P (bf16 MFMA, global-direct fragments),
// then V = od/(P + S) gated. 4 waves/block (same A-row band -> L1 reuse).
// Writes V32 (fp32), V16, VT16.
__global__ __launch_bounds__(256) void v_kernel(const unsigned short* __restrict__ P16,
                                                const unsigned short* __restrict__ PT16,
                                                const float* __restrict__ od,
                                                float* __restrict__ V32,
                                                unsigned short* __restrict__ V16,
                                                unsigned short* __restrict__ VT16) {
    int t = blockIdx.x * 4 + (threadIdx.x >> 6);
    int i0 = (t / NT) * 16, j0 = (t % NT) * 16;
    int lane = threadIdx.x & 63;
    int col = lane & 15, quad = lane >> 4;
    v4f acc0 = {0.f, 0.f, 0.f, 0.f};
    v4f acc1 = {0.f, 0.f, 0.f, 0.f};
    // A[m=col][k=quad*8+...] from P16 rows; B[k][n=col] from PT16 rows.
    const short8* arow = (const short8*)(P16 + (i0 + col) * NN + quad * 8);
    const short8* brow = (const short8*)(PT16 + (j0 + col) * NN + quad * 8);
#pragma unroll
    for (int k0 = 0; k0 < NN / 64; ++k0) {       // 6 double-steps, 2 indep chains
        acc0 = __builtin_amdgcn_mfma_f32_16x16x32_bf16(arow[k0 * 8],     brow[k0 * 8],     acc0, 0, 0, 0);
        acc1 = __builtin_amdgcn_mfma_f32_16x16x32_bf16(arow[k0 * 8 + 4], brow[k0 * 8 + 4], acc1, 0, 0, 0);
    }
#pragma unroll
    for (int r = 0; r < 4; ++r) {
        int i = i0 + quad * 4 + r, j = j0 + col;
        int idx = i * NN + j;
        float denom = bf2f(P16[idx]) + acc0[r] + acc1[r];
        float o = od[idx];
        float v = (i != j && o > 0.0f && denom > 0.0f) ? o / denom : 0.0f;
        V32[idx] = v;
        unsigned short h = f2bf(v);
        V16[idx] = h;
        VT16[j * NN + i] = h;
    }
}

// K3: one wave per 16x16 tile: W = V*P^T (A=V16 rows, Bt=P16 rows),
// U = P^T*V (A=PT16 rows, Bt=VT16 rows); out = p_exact*(V32 + W + U).
// 4 waves/block.
__global__ __launch_bounds__(256) void flows_kernel(const unsigned short* __restrict__ P16,
                                                    const unsigned short* __restrict__ PT16,
                                                    const unsigned short* __restrict__ V16,
                                                    const unsigned short* __restrict__ VT16,
                                                    const float* __restrict__ V32,
                                                    const int* __restrict__ adj,
                                                    const float* __restrict__ dist,
                                                    const int* __restrict__ lam_ptr,
                                                    float* __restrict__ out) {
    int t = blockIdx.x * 4 + (threadIdx.x >> 6);
    int i0 = (t / NT) * 16, j0 = (t % NT) * 16;
    int lane = threadIdx.x & 63;
    int col = lane & 15, quad = lane >> 4;
    v4f accW = {0.f, 0.f, 0.f, 0.f};
    v4f accU = {0.f, 0.f, 0.f, 0.f};
    const short8* aW = (const short8*)(V16 + (i0 + col) * NN + quad * 8);
    const short8* bW = (const short8*)(P16 + (j0 + col) * NN + quad * 8);
    const short8* aU = (const short8*)(PT16 + (i0 + col) * NN + quad * 8);
    const short8* bU = (const short8*)(VT16 + (j0 + col) * NN + quad * 8);
#pragma unroll
    for (int k0 = 0; k0 < NN / 32; ++k0) {       // 12 steps, 2 indep chains
        accW = __builtin_amdgcn_mfma_f32_16x16x32_bf16(aW[k0 * 4], bW[k0 * 4], accW, 0, 0, 0);
        accU = __builtin_amdgcn_mfma_f32_16x16x32_bf16(aU[k0 * 4], bU[k0 * 4], accU, 0, 0, 0);
    }
    float lam = (float)(*lam_ptr);
#pragma unroll
    for (int r = 0; r < 4; ++r) {
        int i = i0 + quad * 4 + r, j = j0 + col;
        int idx = i * NN + j;
        float p = (adj[idx] > 0 && i != j) ? __expf(-lam * dist[idx]) : 0.0f;
        out[idx] = p * (V32[idx] + accW[r] + accU[r]);
    }
}

extern "C" void kernel_launch(void* const* d_in, const int* in_sizes, int n_in,
                              void* d_out, int out_size, void* d_ws, size_t ws_size,
                              hipStream_t stream) {
    const float* od   = (const float*)d_in[0];
    const int*   adj  = (const int*)d_in[1];
    const float* dist = (const float*)d_in[2];
    const int*   lam  = (const int*)d_in[3];
    // d_in[4] = capacity (unused: max_iter=1, BPR update happens after output)
    float* out = (float*)d_out;

    // workspace layout (16B-aligned; bf16 arrays are NN*NN*2 = 294912 B each)
    unsigned short* P16  = (unsigned short*)d_ws;
    unsigned short* PT16 = P16 + NN * NN;
    unsigned short* V16  = PT16 + NN * NN;
    unsigned short* VT16 = V16 + NN * NN;
    float*          V32  = (float*)(VT16 + NN * NN);

    build_p_kernel<<<NBLK, 256, 0, stream>>>(adj, dist, lam, P16, PT16);
    v_kernel<<<NBLK, 256, 0, stream>>>(P16, PT16, od, V32, V16, VT16);
    flows_kernel<<<NBLK, 256, 0, stream>>>(P16, PT16, V16, VT16, V32, adj, dist, lam, out);
}

// Round 5
// 75.287 us; speedup vs baseline: 1.6738x; 1.0142x over previous
//
#include <hip/hip_runtime.h>
#include <math.h>

#define NN 384
#define NT 24              // NN/16 tiles per dim
#define NTILES (NT * NT)   // 576

typedef __attribute__((ext_vector_type(8))) short short8;   // 8 bf16 (4 VGPRs)
typedef __attribute__((ext_vector_type(4))) float v4f;      // 4 fp32 acc
typedef __attribute__((ext_vector_type(4))) int int4v;
typedef __attribute__((ext_vector_type(4))) float float4v;
typedef __attribute__((ext_vector_type(4))) short short4v;

__device__ __forceinline__ unsigned short f2bf(float f) {
    union { float f; unsigned u; } v; v.f = f;
    return (unsigned short)((v.u + 0x7FFFu + ((v.u >> 16) & 1u)) >> 16);
}
__device__ __forceinline__ float bf2f(unsigned short h) {
    union { unsigned u; float f; } v; v.u = ((unsigned)h) << 16;
    return v.f;
}

// K1: P16[i][j] = bf16(exp(-lam*dist) gated), PT16 = transpose.
// 576 blocks x 64 thr (max CU spread), x4 vectorized: 16B coalesced loads,
// 8B P16 stores. PT16 is a 2B transposed scatter (L2-absorbed, 0.3 MB total).
__global__ __launch_bounds__(64) void build_p_kernel(const int* __restrict__ adj,
                                                     const float* __restrict__ dist,
                                                     const int* __restrict__ lam_ptr,
                                                     unsigned short* __restrict__ P16,
                                                     unsigned short* __restrict__ PT16) {
    const float lam = (float)(*lam_ptr);
    int tid = blockIdx.x * 64 + threadIdx.x;     // 36864 threads
    int idx0 = tid * 4;                          // NN*NN = 147456 = 36864*4
    int i = idx0 / NN;
    int jb = idx0 - i * NN;                      // multiple of 4 -> no row crossing
    int4v   a4 = *(const int4v*)(adj + idx0);
    float4v d4 = *(const float4v*)(dist + idx0);
    short4v h4;
#pragma unroll
    for (int u = 0; u < 4; ++u) {
        int j = jb + u;
        float p = (a4[u] > 0 && i != j) ? __expf(-lam * d4[u]) : 0.0f;
        unsigned short h = f2bf(p);
        h4[u] = (short)h;
        PT16[j * NN + i] = h;
    }
    *(short4v*)(P16 + idx0) = h4;
}

// K2: one wave per 16x16 tile of S = P*P (bf16 MFMA, global-direct fragments),
// then V = od/(P + S) gated. 576 blocks x 64 thr (best-measured shape, R0),
// dual accumulator chains (R4). Writes V32 (fp32), V16, VT16.
__global__ __launch_bounds__(64) void v_kernel(const unsigned short* __restrict__ P16,
                                               const unsigned short* __restrict__ PT16,
                                               const float* __restrict__ od,
                                               float* __restrict__ V32,
                                               unsigned short* __restrict__ V16,
                                               unsigned short* __restrict__ VT16) {
    int t = blockIdx.x;
    int i0 = (t / NT) * 16, j0 = (t % NT) * 16;
    int lane = threadIdx.x;
    int col = lane & 15, quad = lane >> 4;
    v4f acc0 = {0.f, 0.f, 0.f, 0.f};
    v4f acc1 = {0.f, 0.f, 0.f, 0.f};
    // A[m=col][k] from P16 rows; B[k][n=col] from PT16 rows.
    const short8* arow = (const short8*)(P16 + (i0 + col) * NN + quad * 8);
    const short8* brow = (const short8*)(PT16 + (j0 + col) * NN + quad * 8);
#pragma unroll
    for (int k0 = 0; k0 < NN / 64; ++k0) {       // 6 double-steps, 2 indep chains
        acc0 = __builtin_amdgcn_mfma_f32_16x16x32_bf16(arow[k0 * 8],     brow[k0 * 8],     acc0, 0, 0, 0);
        acc1 = __builtin_amdgcn_mfma_f32_16x16x32_bf16(arow[k0 * 8 + 4], brow[k0 * 8 + 4], acc1, 0, 0, 0);
    }
#pragma unroll
    for (int r = 0; r < 4; ++r) {
        int i = i0 + quad * 4 + r, j = j0 + col;
        int idx = i * NN + j;
        float denom = bf2f(P16[idx]) + acc0[r] + acc1[r];
        float o = od[idx];
        float v = (i != j && o > 0.0f && denom > 0.0f) ? o / denom : 0.0f;
        V32[idx] = v;
        unsigned short h = f2bf(v);
        V16[idx] = h;
        VT16[j * NN + i] = h;
    }
}

// K3: one wave per 16x16 tile: W = V*P^T (A=V16 rows, Bt=P16 rows),
// U = P^T*V (A=PT16 rows, Bt=VT16 rows); out = p_exact*(V32 + W + U).
// 576 blocks x 64 thr, dual chains.
__global__ __launch_bounds__(64) void flows_kernel(const unsigned short* __restrict__ P16,
                                                   const unsigned short* __restrict__ PT16,
                                                   const unsigned short* __restrict__ V16,
                                                   const unsigned short* __restrict__ VT16,
                                                   const float* __restrict__ V32,
                                                   const int* __restrict__ adj,
                                                   const float* __restrict__ dist,
                                                   const int* __restrict__ lam_ptr,
                                                   float* __restrict__ out) {
    int t = blockIdx.x;
    int i0 = (t / NT) * 16, j0 = (t % NT) * 16;
    int lane = threadIdx.x;
    int col = lane & 15, quad = lane >> 4;
    v4f accW = {0.f, 0.f, 0.f, 0.f};
    v4f accU = {0.f, 0.f, 0.f, 0.f};
    const short8* aW = (const short8*)(V16 + (i0 + col) * NN + quad * 8);
    const short8* bW = (const short8*)(P16 + (j0 + col) * NN + quad * 8);
    const short8* aU = (const short8*)(PT16 + (i0 + col) * NN + quad * 8);
    const short8* bU = (const short8*)(VT16 + (j0 + col) * NN + quad * 8);
#pragma unroll
    for (int k0 = 0; k0 < NN / 32; ++k0) {       // 12 steps, 2 indep chains
        accW = __builtin_amdgcn_mfma_f32_16x16x32_bf16(aW[k0 * 4], bW[k0 * 4], accW, 0, 0, 0);
        accU = __builtin_amdgcn_mfma_f32_16x16x32_bf16(aU[k0 * 4], bU[k0 * 4], accU, 0, 0, 0);
    }
    float lam = (float)(*lam_ptr);
#pragma unroll
    for (int r = 0; r < 4; ++r) {
        int i = i0 + quad * 4 + r, j = j0 + col;
        int idx = i * NN + j;
        float p = (adj[idx] > 0 && i != j) ? __expf(-lam * dist[idx]) : 0.0f;
        out[idx] = p * (V32[idx] + accW[r] + accU[r]);
    }
}

extern "C" void kernel_launch(void* const* d_in, const int* in_sizes, int n_in,
                              void* d_out, int out_size, void* d_ws, size_t ws_size,
                              hipStream_t stream) {
    const float* od   = (const float*)d_in[0];
    const int*   adj  = (const int*)d_in[1];
    const float* dist = (const float*)d_in[2];
    const int*   lam  = (const int*)d_in[3];
    // d_in[4] = capacity (unused: max_iter=1, BPR update happens after output)
    float* out = (float*)d_out;

    // workspace layout (16B-aligned; bf16 arrays are NN*NN*2 = 294912 B each)
    unsigned short* P16  = (unsigned short*)d_ws;
    unsigned short* PT16 = P16 + NN * NN;
    unsigned short* V16  = PT16 + NN * NN;
    unsigned short* VT16 = V16 + NN * NN;
    float*          V32  = (float*)(VT16 + NN * NN);

    build_p_kernel<<<NTILES, 64, 0, stream>>>(adj, dist, lam, P16, PT16);
    v_kernel<<<NTILES, 64, 0, stream>>>(P16, PT16, od, V32, V16, VT16);
    flows_kernel<<<NTILES, 64, 0, stream>>>(P16, PT16, V16, VT16, V32, adj, dist, lam, out);
}